// Round 13
// baseline (115.908 us; speedup 1.0000x reference)
//
#include <hip/hip_runtime.h>
#include <math.h>

#define N_PTS 16384
#define M_TGT 16384
#define TPN 8192
#define DUB2 4.0f
#define BMASK_WORDS (4*64*64*64/32)

__device__ __forceinline__ unsigned int mono_key(float f) {
    unsigned int u = __float_as_uint(f);
    return (u & 0x80000000u) ? ~u : (u | 0x80000000u);
}

// 33 integer offsets with dx^2+dy^2+dz^2 <= 4, grouped by d2 = 0,1,2,3,4.
__device__ const signed char NOFF[33][3] = {
    {0,0,0},
    {1,0,0},{-1,0,0},{0,1,0},{0,-1,0},{0,0,1},{0,0,-1},
    {1,1,0},{1,-1,0},{-1,1,0},{-1,-1,0},{1,0,1},{1,0,-1},{-1,0,1},{-1,0,-1},
    {0,1,1},{0,1,-1},{0,-1,1},{0,-1,-1},
    {1,1,1},{1,1,-1},{1,-1,1},{1,-1,-1},{-1,1,1},{-1,1,-1},{-1,-1,1},{-1,-1,-1},
    {2,0,0},{-2,0,0},{0,2,0},{0,-2,0},{0,0,2},{0,0,-2}
};

// K1: fea_up = relu(fea @ Wup); pred = fea_up @ Wcls.
// 64 rows/block, 4x4 register tile per thread, fs stored TRANSPOSED [k][row]
// so one b128 read feeds 4 rows -> LDS cyc/FMA 4.45 -> 1.5 (was LDS-bound).
// Accumulation order per output unchanged (ascending k, fmaf chain).
// Also zeroes bmask (128 words/block x 256 blocks) before k_selscat's atomicOr.
__global__ __launch_bounds__(256) void k_gemm(const float* __restrict__ fea,
        const float* __restrict__ Wup, const float* __restrict__ Wcls,
        float* __restrict__ out_pred, float* __restrict__ out_fea,
        unsigned int* __restrict__ bmask) {
    __shared__ float Ws[64 * 64];      // [k][n]
    __shared__ float fs[64 * 68];      // [k][row], stride 68 (aligned, conflict-light)
    const int tid = threadIdx.x;
    const int r0 = blockIdx.x * 64;

    if (tid < 128) bmask[blockIdx.x * 128 + tid] = 0u;   // 256*128 = 32768 words

    for (int t = tid; t < 1024; t += 256)
        ((float4*)Ws)[t] = ((const float4*)Wup)[t];
    #pragma unroll
    for (int q = 0; q < 4; ++q) {                        // stage fea transposed
        int idx = tid + q * 256;                         // 1024 float4s
        int r = idx >> 4, c4 = idx & 15;
        float4 v = ((const float4*)(fea + (r0 + r) * 64))[c4];
        fs[(c4*4 + 0) * 68 + r] = v.x;
        fs[(c4*4 + 1) * 68 + r] = v.y;
        fs[(c4*4 + 2) * 68 + r] = v.z;
        fs[(c4*4 + 3) * 68 + r] = v.w;
    }
    __syncthreads();

    const int cg = tid & 15;           // col group: cols cg*4..+3
    const int rg = tid >> 4;           // row group: rows rg*4..+3
    float4 acc0 = {0,0,0,0}, acc1 = {0,0,0,0}, acc2 = {0,0,0,0}, acc3 = {0,0,0,0};
    #pragma unroll
    for (int k = 0; k < 64; ++k) {
        float4 w = *(const float4*)&Ws[k * 64 + cg * 4];
        float4 f = *(const float4*)&fs[k * 68 + rg * 4];
        acc0.x=fmaf(f.x,w.x,acc0.x); acc0.y=fmaf(f.x,w.y,acc0.y); acc0.z=fmaf(f.x,w.z,acc0.z); acc0.w=fmaf(f.x,w.w,acc0.w);
        acc1.x=fmaf(f.y,w.x,acc1.x); acc1.y=fmaf(f.y,w.y,acc1.y); acc1.z=fmaf(f.y,w.z,acc1.z); acc1.w=fmaf(f.y,w.w,acc1.w);
        acc2.x=fmaf(f.z,w.x,acc2.x); acc2.y=fmaf(f.z,w.y,acc2.y); acc2.z=fmaf(f.z,w.z,acc2.z); acc2.w=fmaf(f.z,w.w,acc2.w);
        acc3.x=fmaf(f.w,w.x,acc3.x); acc3.y=fmaf(f.w,w.y,acc3.y); acc3.z=fmaf(f.w,w.z,acc3.z); acc3.w=fmaf(f.w,w.w,acc3.w);
    }
    float4 wc = ((const float4*)Wcls)[cg];
    #pragma unroll
    for (int i = 0; i < 4; ++i) {
        float4 a = (i==0) ? acc0 : (i==1) ? acc1 : (i==2) ? acc2 : acc3;
        a.x = fmaxf(a.x, 0.f); a.y = fmaxf(a.y, 0.f);
        a.z = fmaxf(a.z, 0.f); a.w = fmaxf(a.w, 0.f);
        const int row = r0 + rg * 4 + i;
        *(float4*)&out_fea[row * 64 + cg * 4] = a;
        float s = a.x*wc.x + a.y*wc.y + a.z*wc.z + a.w*wc.w;
        for (int off = 1; off < 16; off <<= 1) s += __shfl_xor(s, off, 16);
        if (cg == 0) out_pred[row] = s;
    }
}

// K2: block 0 = exact radix-256 select of the 8192nd smallest; blocks 1..16
// build the target bitmask. Pass-0 histogram uses ballot-dedup (one LDS atomic
// per distinct bin per wave -- GEMM-output exponents cluster into few bins);
// 256-bin scan done by a single wave via shfl (2 syncs instead of 16).
__global__ __launch_bounds__(1024) void k_selscat(const float* __restrict__ p,
        const int* __restrict__ tc, unsigned int* __restrict__ bmask,
        float* __restrict__ thres_out) {
    __shared__ unsigned int keys[N_PTS];        // 64 KB
    __shared__ unsigned int whist[16][256];     // 16 KB
    __shared__ unsigned int hist[256];
    __shared__ unsigned int scanb[256];
    __shared__ unsigned int sh_prefix, sh_rank;
    const int tid = threadIdx.x;
    const int lane = tid & 63;

    if (blockIdx.x != 0) {                      // bitmask build
        const int id = (blockIdx.x - 1) * 1024 + tid;
        int4 c = *(const int4*)&tc[id * 4];
        int key = ((c.x * 64 + c.y) * 64 + c.z) * 64 + c.w;
        atomicOr(&bmask[key >> 5], 1u << (key & 31));
        return;
    }

    const int w = tid >> 6;
    for (int i = tid; i < N_PTS / 4; i += 1024) {
        float4 v = ((const float4*)p)[i];
        keys[i*4 + 0] = mono_key(v.x);
        keys[i*4 + 1] = mono_key(v.y);
        keys[i*4 + 2] = mono_key(v.z);
        keys[i*4 + 3] = mono_key(v.w);
    }
    if (tid == 0) { sh_prefix = 0u; sh_rank = TPN - 1; }
    __syncthreads();

    for (int pass = 0; pass < 4; ++pass) {
        const int shift = 24 - pass * 8;
        const unsigned int prefix = sh_prefix;
        const unsigned int rank = sh_rank;
        for (int t = tid; t < 16 * 256; t += 1024) ((unsigned int*)whist)[t] = 0u;
        __syncthreads();
        for (int i = tid; i < N_PTS; i += 1024) {
            unsigned int u = keys[i];
            unsigned int bin = (u >> shift) & 255u;
            if (pass == 0) {
                // ballot-dedup: one atomic per distinct bin per wave
                unsigned long long todo = ~0ull;
                while (todo) {
                    int L = __ffsll(todo) - 1;
                    unsigned int bL = __shfl(bin, L);
                    unsigned long long m = __ballot(bin == bL);
                    if (lane == L) atomicAdd(&whist[w][bL], (unsigned int)__popcll(m));
                    todo &= ~m;
                }
            } else {
                if ((u >> (shift + 8)) == prefix) atomicAdd(&whist[w][bin], 1u);
            }
        }
        __syncthreads();
        if (tid < 256) {
            unsigned int s = 0u;
            #pragma unroll
            for (int ww = 0; ww < 16; ++ww) s += whist[ww][tid];
            hist[tid] = s;
        }
        __syncthreads();
        if (tid < 64) {                         // single-wave scan of 256 bins
            uint4 h = ((const uint4*)hist)[tid];
            unsigned int s0 = h.x, s1 = s0 + h.y, s2 = s1 + h.z, s3 = s2 + h.w;
            unsigned int tot = s3;
            for (int d = 1; d < 64; d <<= 1) {
                unsigned int v = __shfl_up(tot, d);
                if (lane >= d) tot += v;
            }
            unsigned int base = tot - s3;       // exclusive prefix of this lane's 4 bins
            scanb[tid*4 + 0] = base + s0;
            scanb[tid*4 + 1] = base + s1;
            scanb[tid*4 + 2] = base + s2;
            scanb[tid*4 + 3] = base + s3;
        }
        __syncthreads();
        if (tid < 256) {
            unsigned int hi = scanb[tid];
            unsigned int lo = hi - hist[tid];
            if (rank >= lo && rank < hi) {
                sh_prefix = (prefix << 8) | (unsigned int)tid;
                sh_rank = rank - lo;
            }
        }
        __syncthreads();
    }
    if (tid == 0) {
        unsigned int u = sh_prefix;
        thres_out[0] = (u & 0x80000000u) ? __uint_as_float(u ^ 0x80000000u)
                                         : __uint_as_float(~u);
    }
}

// K3: epilogue with bitmask-probe NN (dists only exposed when <=4; integer
// coords => probe 33 cells in increasing-d2 groups = exact reference output).
__global__ __launch_bounds__(256) void k_final(const int* __restrict__ coords,
        const unsigned int* __restrict__ bmask, const float* __restrict__ thres_p,
        const float* __restrict__ out_pred, float* __restrict__ out_fea,
        float* __restrict__ out_keep, float* __restrict__ out_kt,
        float* __restrict__ out_loss) {
    __shared__ float kscale[64];
    const int tid = threadIdx.x;
    const int r0 = blockIdx.x * 64;
    if (tid < 64) {
        const int i = r0 + tid;
        float p = out_pred[i];
        float thres = thres_p[0];
        int4 c = *(const int4*)&coords[i * 4];
        const int b = c.x, x = c.y, y = c.z, z = c.w;
        int key0 = ((b * 64 + x) * 64 + y) * 64 + z;
        bool kt = (bmask[key0 >> 5] >> (key0 & 31)) & 1u;
        float dists;
        if (kt) {
            dists = 0.f;
        } else {
            dists = 5.f;                     // sentinel > DUB2: "not found"
            int t = 1;
            #pragma unroll
            for (int g = 1; g <= 4; ++g) {
                const int gend = (g == 1) ? 7 : (g == 2) ? 19 : (g == 3) ? 27 : 33;
                bool hit = false;
                for (; t < gend; ++t) {
                    int ox = x + NOFF[t][0], oy = y + NOFF[t][1], oz = z + NOFF[t][2];
                    if (((unsigned)ox | (unsigned)oy | (unsigned)oz) < 64u) {
                        int key = ((b * 64 + ox) * 64 + oy) * 64 + oz;
                        hit |= (bmask[key >> 5] >> (key & 31)) & 1u;
                    }
                }
                if (hit) { dists = (float)g; break; }
            }
        }
        bool keep0 = (p <= thres);
        bool pm = (p > DUB2), tm = (dists > DUB2);
        float loss = (pm && tm) ? p : ((!pm && tm) ? DUB2 : dists);
        bool kf = keep0 || kt;
        out_keep[i] = kf ? 1.f : 0.f;
        out_kt[i]  = kt ? 1.f : 0.f;
        out_loss[i] = loss;
        kscale[tid] = kf ? 1.f : 0.f;
    }
    __syncthreads();
    float4* fbase = (float4*)(out_fea + r0 * 64);
    #pragma unroll
    for (int q = 0; q < 4; ++q) {
        int v = tid + q * 256;               // 64 rows x 16 float4 = 1024
        float sc = kscale[v >> 4];
        float4 xv = fbase[v];
        xv.x *= sc; xv.y *= sc; xv.z *= sc; xv.w *= sc;
        fbase[v] = xv;
    }
}

extern "C" void kernel_launch(void* const* d_in, const int* in_sizes, int n_in,
                              void* d_out, int out_size, void* d_ws, size_t ws_size,
                              hipStream_t stream) {
    const float* fea     = (const float*)d_in[0];
    const float* Wup     = (const float*)d_in[1];
    const float* Wcls    = (const float*)d_in[2];
    const int*   coords  = (const int*)d_in[3];
    const int*   tcoords = (const int*)d_in[4];

    float* out      = (float*)d_out;
    float* out_pred = out;
    float* out_fea  = out + N_PTS;
    float* out_keep = out + N_PTS + N_PTS * 64;
    float* out_kt   = out_keep + N_PTS;
    float* out_loss = out_kt + N_PTS;

    char* ws = (char*)d_ws;
    unsigned int* bmask   = (unsigned int*)(ws + 64);          // 128 KB -> 131136
    float*        thres   = (float*)(ws + 131136);             // 4 B

    k_gemm   <<<N_PTS / 64, 256, 0, stream>>>(fea, Wup, Wcls, out_pred, out_fea, bmask);
    k_selscat<<<1 + M_TGT / 1024, 1024, 0, stream>>>(out_pred, tcoords, bmask, thres);
    k_final  <<<N_PTS / 64, 256, 0, stream>>>(coords, bmask, thres,
                                              out_pred, out_fea, out_keep, out_kt, out_loss);
}

// Round 14
// 41.292 us; speedup vs baseline: 2.8070x; 2.8070x over previous
//
#include <hip/hip_runtime.h>
#include <math.h>

#define N_PTS 16384
#define M_TGT 16384
#define TPN 8192
#define DUB2 4.0f
#define BMASK_WORDS (4*64*64*64/32)

__device__ __forceinline__ unsigned int mono_key(float f) {
    unsigned int u = __float_as_uint(f);
    return (u & 0x80000000u) ? ~u : (u | 0x80000000u);
}

// 33 integer offsets with dx^2+dy^2+dz^2 <= 4, grouped by d2 = 0,1,2,3,4.
__device__ const signed char NOFF[33][3] = {
    {0,0,0},
    {1,0,0},{-1,0,0},{0,1,0},{0,-1,0},{0,0,1},{0,0,-1},
    {1,1,0},{1,-1,0},{-1,1,0},{-1,-1,0},{1,0,1},{1,0,-1},{-1,0,1},{-1,0,-1},
    {0,1,1},{0,1,-1},{0,-1,1},{0,-1,-1},
    {1,1,1},{1,1,-1},{1,-1,1},{1,-1,-1},{-1,1,1},{-1,1,-1},{-1,-1,1},{-1,-1,-1},
    {2,0,0},{-2,0,0},{0,2,0},{0,-2,0},{0,0,2},{0,0,-2}
};

// K1 (reverted to round-11 proven version): fea_up = relu(fea @ Wup);
// pred = fea_up @ Wcls. 16 rows/block. The round-13 4x4-register-tile variant
// spilled to scratch (256 VGPR, 300 MB scratch traffic, 86+ us) — do not
// reintroduce runtime-indexed accumulator tiles (rule #20).
// Also zeroes bmask (32 words/block x 1024 blocks) before k_selscat's atomicOr.
__global__ __launch_bounds__(256) void k_gemm(const float* __restrict__ fea,
        const float* __restrict__ Wup, const float* __restrict__ Wcls,
        float* __restrict__ out_pred, float* __restrict__ out_fea,
        unsigned int* __restrict__ bmask) {
    __shared__ float Ws[64 * 64];
    __shared__ float fs[16 * 68];
    const int tid = threadIdx.x;
    const int r0 = blockIdx.x * 16;

    if (tid < 32) bmask[blockIdx.x * 32 + tid] = 0u;

    for (int t = tid; t < 1024; t += 256)
        ((float4*)Ws)[t] = ((const float4*)Wup)[t];
    {
        float4 v = ((const float4*)(fea + r0 * 64))[tid];
        int r = tid >> 4, c = (tid & 15) * 4;
        fs[r*68 + c + 0] = v.x; fs[r*68 + c + 1] = v.y;
        fs[r*68 + c + 2] = v.z; fs[r*68 + c + 3] = v.w;
    }
    __syncthreads();

    const int cg = tid & 15;
    const int r  = tid >> 4;
    float a0 = 0.f, a1 = 0.f, a2 = 0.f, a3 = 0.f;
    const float* fr = fs + r * 68;
    #pragma unroll
    for (int k = 0; k < 64; ++k) {
        float f = fr[k];
        float4 w = *(const float4*)&Ws[k * 64 + cg * 4];
        a0 = fmaf(f, w.x, a0); a1 = fmaf(f, w.y, a1);
        a2 = fmaf(f, w.z, a2); a3 = fmaf(f, w.w, a3);
    }
    a0 = fmaxf(a0, 0.f); a1 = fmaxf(a1, 0.f);
    a2 = fmaxf(a2, 0.f); a3 = fmaxf(a3, 0.f);
    const int row = r0 + r;
    *(float4*)&out_fea[row * 64 + cg * 4] = make_float4(a0, a1, a2, a3);

    float4 wc = *(const float4*)&Wcls[cg * 4];
    float s = a0*wc.x + a1*wc.y + a2*wc.z + a3*wc.w;
    for (int off = 1; off < 16; off <<= 1) s += __shfl_xor(s, off, 16);
    if (cg == 0) out_pred[row] = s;
}

// K2: block 0 = exact radix-256 select of the 8192nd smallest; blocks 1..16
// build the target bitmask. Pass-0 histogram uses ballot-dedup (one LDS atomic
// per distinct bin per wave -- GEMM-output exponents cluster into few bins);
// 256-bin scan done by a single wave via shfl (2 syncs instead of 16).
__global__ __launch_bounds__(1024) void k_selscat(const float* __restrict__ p,
        const int* __restrict__ tc, unsigned int* __restrict__ bmask,
        float* __restrict__ thres_out) {
    __shared__ unsigned int keys[N_PTS];        // 64 KB
    __shared__ unsigned int whist[16][256];     // 16 KB
    __shared__ unsigned int hist[256];
    __shared__ unsigned int scanb[256];
    __shared__ unsigned int sh_prefix, sh_rank;
    const int tid = threadIdx.x;
    const int lane = tid & 63;

    if (blockIdx.x != 0) {                      // bitmask build
        const int id = (blockIdx.x - 1) * 1024 + tid;
        int4 c = *(const int4*)&tc[id * 4];
        int key = ((c.x * 64 + c.y) * 64 + c.z) * 64 + c.w;
        atomicOr(&bmask[key >> 5], 1u << (key & 31));
        return;
    }

    const int w = tid >> 6;
    for (int i = tid; i < N_PTS / 4; i += 1024) {
        float4 v = ((const float4*)p)[i];
        keys[i*4 + 0] = mono_key(v.x);
        keys[i*4 + 1] = mono_key(v.y);
        keys[i*4 + 2] = mono_key(v.z);
        keys[i*4 + 3] = mono_key(v.w);
    }
    if (tid == 0) { sh_prefix = 0u; sh_rank = TPN - 1; }
    __syncthreads();

    for (int pass = 0; pass < 4; ++pass) {
        const int shift = 24 - pass * 8;
        const unsigned int prefix = sh_prefix;
        const unsigned int rank = sh_rank;
        for (int t = tid; t < 16 * 256; t += 1024) ((unsigned int*)whist)[t] = 0u;
        __syncthreads();
        for (int i = tid; i < N_PTS; i += 1024) {
            unsigned int u = keys[i];
            unsigned int bin = (u >> shift) & 255u;
            if (pass == 0) {
                // ballot-dedup: one atomic per distinct bin per wave
                unsigned long long todo = ~0ull;
                while (todo) {
                    int L = __ffsll(todo) - 1;
                    unsigned int bL = __shfl(bin, L);
                    unsigned long long m = __ballot(bin == bL);
                    if (lane == L) atomicAdd(&whist[w][bL], (unsigned int)__popcll(m));
                    todo &= ~m;
                }
            } else {
                if ((u >> (shift + 8)) == prefix) atomicAdd(&whist[w][bin], 1u);
            }
        }
        __syncthreads();
        if (tid < 256) {
            unsigned int s = 0u;
            #pragma unroll
            for (int ww = 0; ww < 16; ++ww) s += whist[ww][tid];
            hist[tid] = s;
        }
        __syncthreads();
        if (tid < 64) {                         // single-wave scan of 256 bins
            uint4 h = ((const uint4*)hist)[tid];
            unsigned int s0 = h.x, s1 = s0 + h.y, s2 = s1 + h.z, s3 = s2 + h.w;
            unsigned int tot = s3;
            for (int d = 1; d < 64; d <<= 1) {
                unsigned int v = __shfl_up(tot, d);
                if (lane >= d) tot += v;
            }
            unsigned int base = tot - s3;       // exclusive prefix of this lane's 4 bins
            scanb[tid*4 + 0] = base + s0;
            scanb[tid*4 + 1] = base + s1;
            scanb[tid*4 + 2] = base + s2;
            scanb[tid*4 + 3] = base + s3;
        }
        __syncthreads();
        if (tid < 256) {
            unsigned int hi = scanb[tid];
            unsigned int lo = hi - hist[tid];
            if (rank >= lo && rank < hi) {
                sh_prefix = (prefix << 8) | (unsigned int)tid;
                sh_rank = rank - lo;
            }
        }
        __syncthreads();
    }
    if (tid == 0) {
        unsigned int u = sh_prefix;
        thres_out[0] = (u & 0x80000000u) ? __uint_as_float(u ^ 0x80000000u)
                                         : __uint_as_float(~u);
    }
}

// K3: epilogue with bitmask-probe NN (dists only exposed when <=4; integer
// coords => probe 33 cells in increasing-d2 groups = exact reference output).
__global__ __launch_bounds__(256) void k_final(const int* __restrict__ coords,
        const unsigned int* __restrict__ bmask, const float* __restrict__ thres_p,
        const float* __restrict__ out_pred, float* __restrict__ out_fea,
        float* __restrict__ out_keep, float* __restrict__ out_kt,
        float* __restrict__ out_loss) {
    __shared__ float kscale[64];
    const int tid = threadIdx.x;
    const int r0 = blockIdx.x * 64;
    if (tid < 64) {
        const int i = r0 + tid;
        float p = out_pred[i];
        float thres = thres_p[0];
        int4 c = *(const int4*)&coords[i * 4];
        const int b = c.x, x = c.y, y = c.z, z = c.w;
        int key0 = ((b * 64 + x) * 64 + y) * 64 + z;
        bool kt = (bmask[key0 >> 5] >> (key0 & 31)) & 1u;
        float dists;
        if (kt) {
            dists = 0.f;
        } else {
            dists = 5.f;                     // sentinel > DUB2: "not found"
            int t = 1;
            #pragma unroll
            for (int g = 1; g <= 4; ++g) {
                const int gend = (g == 1) ? 7 : (g == 2) ? 19 : (g == 3) ? 27 : 33;
                bool hit = false;
                for (; t < gend; ++t) {
                    int ox = x + NOFF[t][0], oy = y + NOFF[t][1], oz = z + NOFF[t][2];
                    if (((unsigned)ox | (unsigned)oy | (unsigned)oz) < 64u) {
                        int key = ((b * 64 + ox) * 64 + oy) * 64 + oz;
                        hit |= (bmask[key >> 5] >> (key & 31)) & 1u;
                    }
                }
                if (hit) { dists = (float)g; break; }
            }
        }
        bool keep0 = (p <= thres);
        bool pm = (p > DUB2), tm = (dists > DUB2);
        float loss = (pm && tm) ? p : ((!pm && tm) ? DUB2 : dists);
        bool kf = keep0 || kt;
        out_keep[i] = kf ? 1.f : 0.f;
        out_kt[i]  = kt ? 1.f : 0.f;
        out_loss[i] = loss;
        kscale[tid] = kf ? 1.f : 0.f;
    }
    __syncthreads();
    float4* fbase = (float4*)(out_fea + r0 * 64);
    #pragma unroll
    for (int q = 0; q < 4; ++q) {
        int v = tid + q * 256;               // 64 rows x 16 float4 = 1024
        float sc = kscale[v >> 4];
        float4 xv = fbase[v];
        xv.x *= sc; xv.y *= sc; xv.z *= sc; xv.w *= sc;
        fbase[v] = xv;
    }
}

extern "C" void kernel_launch(void* const* d_in, const int* in_sizes, int n_in,
                              void* d_out, int out_size, void* d_ws, size_t ws_size,
                              hipStream_t stream) {
    const float* fea     = (const float*)d_in[0];
    const float* Wup     = (const float*)d_in[1];
    const float* Wcls    = (const float*)d_in[2];
    const int*   coords  = (const int*)d_in[3];
    const int*   tcoords = (const int*)d_in[4];

    float* out      = (float*)d_out;
    float* out_pred = out;
    float* out_fea  = out + N_PTS;
    float* out_keep = out + N_PTS + N_PTS * 64;
    float* out_kt   = out_keep + N_PTS;
    float* out_loss = out_kt + N_PTS;

    char* ws = (char*)d_ws;
    unsigned int* bmask   = (unsigned int*)(ws + 64);          // 128 KB -> 131136
    float*        thres   = (float*)(ws + 131136);             // 4 B

    k_gemm   <<<N_PTS / 16, 256, 0, stream>>>(fea, Wup, Wcls, out_pred, out_fea, bmask);
    k_selscat<<<1 + M_TGT / 1024, 1024, 0, stream>>>(out_pred, tcoords, bmask, thres);
    k_final  <<<N_PTS / 64, 256, 0, stream>>>(coords, bmask, thres,
                                              out_pred, out_fea, out_keep, out_kt, out_loss);
}

// Round 16
// 35.978 us; speedup vs baseline: 3.2217x; 1.1477x over previous
//
#include <hip/hip_runtime.h>
#include <math.h>

#define N_PTS 16384
#define M_TGT 16384
#define TPN 8192
#define DUB2 4.0f
#define BMASK_WORDS (4*64*64*64/32)

__device__ __forceinline__ unsigned int mono_key(float f) {
    unsigned int u = __float_as_uint(f);
    return (u & 0x80000000u) ? ~u : (u | 0x80000000u);
}

// 33 integer offsets with dx^2+dy^2+dz^2 <= 4, grouped by d2 = 0,1,2,3,4.
__device__ const signed char NOFF[33][3] = {
    {0,0,0},
    {1,0,0},{-1,0,0},{0,1,0},{0,-1,0},{0,0,1},{0,0,-1},
    {1,1,0},{1,-1,0},{-1,1,0},{-1,-1,0},{1,0,1},{1,0,-1},{-1,0,1},{-1,0,-1},
    {0,1,1},{0,1,-1},{0,-1,1},{0,-1,-1},
    {1,1,1},{1,1,-1},{1,-1,1},{1,-1,-1},{-1,1,1},{-1,1,-1},{-1,-1,1},{-1,-1,-1},
    {2,0,0},{-2,0,0},{0,2,0},{0,-2,0},{0,0,2},{0,0,-2}
};

// K1: fea_up = relu(fea @ Wup); pred = fea_up @ Wcls.
// 64 rows/block, 4 rows x 4 cols per thread. fs stays [row][k] (stride 68,
// round-11 layout; NO transposed scatter staging). Accumulators are 4 named
// float4 with STATIC .x/.y/.z/.w access only; epilogue is 4 explicit blocks
// (round-13's ternary-select/runtime-indexed tile spilled to scratch).
// f reads: 4x ds_read_b32, 16-lane broadcast, rows 272 words apart -> 2-way
// bank alias = free (m136). LDS cyc/FMA ~2.2 vs 4.45 in round 11.
// Per-output fmaf chain identical to round 11 -> bit-identical results.
// Also zeroes bmask (128 words/block x 256 blocks).
__global__ __launch_bounds__(256) void k_gemm(const float* __restrict__ fea,
        const float* __restrict__ Wup, const float* __restrict__ Wcls,
        float* __restrict__ out_pred, float* __restrict__ out_fea,
        unsigned int* __restrict__ bmask) {
    __shared__ float Ws[64 * 64];      // [k][n]
    __shared__ float fs[64 * 68];      // [row][k], stride 68
    const int tid = threadIdx.x;
    const int r0 = blockIdx.x * 64;

    if (tid < 128) bmask[blockIdx.x * 128 + tid] = 0u;   // 256*128 = 32768 words

    for (int t = tid; t < 1024; t += 256)
        ((float4*)Ws)[t] = ((const float4*)Wup)[t];
    #pragma unroll
    for (int q = 0; q < 4; ++q) {                        // 64 rows, row-major staging
        int idx = tid + q * 256;                         // 1024 float4s
        int r = idx >> 4, c = (idx & 15) * 4;
        float4 v = ((const float4*)(fea + (r0 + r) * 64))[idx & 15];
        *(float4*)&fs[r * 68 + c] = v;
    }
    __syncthreads();

    const int cg = tid & 15;           // cols cg*4..+3
    const int rg = tid >> 4;           // rows rg*4..+3 (rg 0..15)
    const float* fr0 = fs + (rg * 4 + 0) * 68;
    const float* fr1 = fs + (rg * 4 + 1) * 68;
    const float* fr2 = fs + (rg * 4 + 2) * 68;
    const float* fr3 = fs + (rg * 4 + 3) * 68;
    float4 acc0 = {0,0,0,0}, acc1 = {0,0,0,0}, acc2 = {0,0,0,0}, acc3 = {0,0,0,0};
    #pragma unroll
    for (int k = 0; k < 64; ++k) {
        float4 w = *(const float4*)&Ws[k * 64 + cg * 4];
        float f0 = fr0[k], f1 = fr1[k], f2 = fr2[k], f3 = fr3[k];
        acc0.x=fmaf(f0,w.x,acc0.x); acc0.y=fmaf(f0,w.y,acc0.y); acc0.z=fmaf(f0,w.z,acc0.z); acc0.w=fmaf(f0,w.w,acc0.w);
        acc1.x=fmaf(f1,w.x,acc1.x); acc1.y=fmaf(f1,w.y,acc1.y); acc1.z=fmaf(f1,w.z,acc1.z); acc1.w=fmaf(f1,w.w,acc1.w);
        acc2.x=fmaf(f2,w.x,acc2.x); acc2.y=fmaf(f2,w.y,acc2.y); acc2.z=fmaf(f2,w.z,acc2.z); acc2.w=fmaf(f2,w.w,acc2.w);
        acc3.x=fmaf(f3,w.x,acc3.x); acc3.y=fmaf(f3,w.y,acc3.y); acc3.z=fmaf(f3,w.z,acc3.z); acc3.w=fmaf(f3,w.w,acc3.w);
    }
    float4 wc = *(const float4*)&Wcls[cg * 4];
    {   // row rg*4+0
        acc0.x=fmaxf(acc0.x,0.f); acc0.y=fmaxf(acc0.y,0.f); acc0.z=fmaxf(acc0.z,0.f); acc0.w=fmaxf(acc0.w,0.f);
        const int row = r0 + rg * 4 + 0;
        *(float4*)&out_fea[row * 64 + cg * 4] = acc0;
        float s = acc0.x*wc.x + acc0.y*wc.y + acc0.z*wc.z + acc0.w*wc.w;
        for (int off = 1; off < 16; off <<= 1) s += __shfl_xor(s, off, 16);
        if (cg == 0) out_pred[row] = s;
    }
    {   // row rg*4+1
        acc1.x=fmaxf(acc1.x,0.f); acc1.y=fmaxf(acc1.y,0.f); acc1.z=fmaxf(acc1.z,0.f); acc1.w=fmaxf(acc1.w,0.f);
        const int row = r0 + rg * 4 + 1;
        *(float4*)&out_fea[row * 64 + cg * 4] = acc1;
        float s = acc1.x*wc.x + acc1.y*wc.y + acc1.z*wc.z + acc1.w*wc.w;
        for (int off = 1; off < 16; off <<= 1) s += __shfl_xor(s, off, 16);
        if (cg == 0) out_pred[row] = s;
    }
    {   // row rg*4+2
        acc2.x=fmaxf(acc2.x,0.f); acc2.y=fmaxf(acc2.y,0.f); acc2.z=fmaxf(acc2.z,0.f); acc2.w=fmaxf(acc2.w,0.f);
        const int row = r0 + rg * 4 + 2;
        *(float4*)&out_fea[row * 64 + cg * 4] = acc2;
        float s = acc2.x*wc.x + acc2.y*wc.y + acc2.z*wc.z + acc2.w*wc.w;
        for (int off = 1; off < 16; off <<= 1) s += __shfl_xor(s, off, 16);
        if (cg == 0) out_pred[row] = s;
    }
    {   // row rg*4+3
        acc3.x=fmaxf(acc3.x,0.f); acc3.y=fmaxf(acc3.y,0.f); acc3.z=fmaxf(acc3.z,0.f); acc3.w=fmaxf(acc3.w,0.f);
        const int row = r0 + rg * 4 + 3;
        *(float4*)&out_fea[row * 64 + cg * 4] = acc3;
        float s = acc3.x*wc.x + acc3.y*wc.y + acc3.z*wc.z + acc3.w*wc.w;
        for (int off = 1; off < 16; off <<= 1) s += __shfl_xor(s, off, 16);
        if (cg == 0) out_pred[row] = s;
    }
}

// K2 (round-11 proven version — ballot-dedup variant was +6 us):
// block 0 = exact radix-256 select; blocks 1..16 build the target bitmask.
__global__ __launch_bounds__(1024) void k_selscat(const float* __restrict__ p,
        const int* __restrict__ tc, unsigned int* __restrict__ bmask,
        float* __restrict__ thres_out) {
    __shared__ unsigned int keys[N_PTS];        // 64 KB
    __shared__ unsigned int whist[16][256];     // 16 KB
    __shared__ unsigned int hist[256];
    __shared__ unsigned int scanb[256];
    __shared__ unsigned int sh_prefix, sh_rank;
    const int tid = threadIdx.x;

    if (blockIdx.x != 0) {                      // bitmask build
        const int id = (blockIdx.x - 1) * 1024 + tid;
        int4 c = *(const int4*)&tc[id * 4];
        int key = ((c.x * 64 + c.y) * 64 + c.z) * 64 + c.w;
        atomicOr(&bmask[key >> 5], 1u << (key & 31));
        return;
    }

    const int w = tid >> 6;
    for (int i = tid; i < N_PTS / 4; i += 1024) {
        float4 v = ((const float4*)p)[i];
        keys[i*4 + 0] = mono_key(v.x);
        keys[i*4 + 1] = mono_key(v.y);
        keys[i*4 + 2] = mono_key(v.z);
        keys[i*4 + 3] = mono_key(v.w);
    }
    if (tid == 0) { sh_prefix = 0u; sh_rank = TPN - 1; }
    __syncthreads();

    for (int pass = 0; pass < 4; ++pass) {
        const int shift = 24 - pass * 8;
        const unsigned int prefix = sh_prefix;
        const unsigned int rank = sh_rank;
        for (int t = tid; t < 16 * 256; t += 1024) ((unsigned int*)whist)[t] = 0u;
        __syncthreads();
        for (int i = tid; i < N_PTS; i += 1024) {
            unsigned int u = keys[i];
            bool match = (pass == 0) || ((u >> (shift + 8)) == prefix);
            if (match) atomicAdd(&whist[w][(u >> shift) & 255u], 1u);
        }
        __syncthreads();
        if (tid < 256) {
            unsigned int s = 0u;
            #pragma unroll
            for (int ww = 0; ww < 16; ++ww) s += whist[ww][tid];
            hist[tid] = s;
            scanb[tid] = s;
        }
        __syncthreads();
        for (int d = 1; d < 256; d <<= 1) {
            unsigned int v = 0u;
            if (tid < 256 && tid >= d) v = scanb[tid - d];
            __syncthreads();
            if (tid < 256) scanb[tid] += v;
            __syncthreads();
        }
        if (tid < 256) {
            unsigned int hi = scanb[tid];
            unsigned int lo = hi - hist[tid];
            if (rank >= lo && rank < hi) {
                sh_prefix = (prefix << 8) | (unsigned int)tid;
                sh_rank = rank - lo;
            }
        }
        __syncthreads();
    }
    if (tid == 0) {
        unsigned int u = sh_prefix;
        thres_out[0] = (u & 0x80000000u) ? __uint_as_float(u ^ 0x80000000u)
                                         : __uint_as_float(~u);
    }
}

// K3: epilogue with bitmask-probe NN (dists only exposed when <=4; integer
// coords => probe 33 cells in increasing-d2 groups = exact reference output).
__global__ __launch_bounds__(256) void k_final(const int* __restrict__ coords,
        const unsigned int* __restrict__ bmask, const float* __restrict__ thres_p,
        const float* __restrict__ out_pred, float* __restrict__ out_fea,
        float* __restrict__ out_keep, float* __restrict__ out_kt,
        float* __restrict__ out_loss) {
    __shared__ float kscale[64];
    const int tid = threadIdx.x;
    const int r0 = blockIdx.x * 64;
    if (tid < 64) {
        const int i = r0 + tid;
        float p = out_pred[i];
        float thres = thres_p[0];
        int4 c = *(const int4*)&coords[i * 4];
        const int b = c.x, x = c.y, y = c.z, z = c.w;
        int key0 = ((b * 64 + x) * 64 + y) * 64 + z;
        bool kt = (bmask[key0 >> 5] >> (key0 & 31)) & 1u;
        float dists;
        if (kt) {
            dists = 0.f;
        } else {
            dists = 5.f;                     // sentinel > DUB2: "not found"
            int t = 1;
            #pragma unroll
            for (int g = 1; g <= 4; ++g) {
                const int gend = (g == 1) ? 7 : (g == 2) ? 19 : (g == 3) ? 27 : 33;
                bool hit = false;
                for (; t < gend; ++t) {
                    int ox = x + NOFF[t][0], oy = y + NOFF[t][1], oz = z + NOFF[t][2];
                    if (((unsigned)ox | (unsigned)oy | (unsigned)oz) < 64u) {
                        int key = ((b * 64 + ox) * 64 + oy) * 64 + oz;
                        hit |= (bmask[key >> 5] >> (key & 31)) & 1u;
                    }
                }
                if (hit) { dists = (float)g; break; }
            }
        }
        bool keep0 = (p <= thres);
        bool pm = (p > DUB2), tm = (dists > DUB2);
        float loss = (pm && tm) ? p : ((!pm && tm) ? DUB2 : dists);
        bool kf = keep0 || kt;
        out_keep[i] = kf ? 1.f : 0.f;
        out_kt[i]  = kt ? 1.f : 0.f;
        out_loss[i] = loss;
        kscale[tid] = kf ? 1.f : 0.f;
    }
    __syncthreads();
    float4* fbase = (float4*)(out_fea + r0 * 64);
    #pragma unroll
    for (int q = 0; q < 4; ++q) {
        int v = tid + q * 256;               // 64 rows x 16 float4 = 1024
        float sc = kscale[v >> 4];
        float4 xv = fbase[v];
        xv.x *= sc; xv.y *= sc; xv.z *= sc; xv.w *= sc;
        fbase[v] = xv;
    }
}

extern "C" void kernel_launch(void* const* d_in, const int* in_sizes, int n_in,
                              void* d_out, int out_size, void* d_ws, size_t ws_size,
                              hipStream_t stream) {
    const float* fea     = (const float*)d_in[0];
    const float* Wup     = (const float*)d_in[1];
    const float* Wcls    = (const float*)d_in[2];
    const int*   coords  = (const int*)d_in[3];
    const int*   tcoords = (const int*)d_in[4];

    float* out      = (float*)d_out;
    float* out_pred = out;
    float* out_fea  = out + N_PTS;
    float* out_keep = out + N_PTS + N_PTS * 64;
    float* out_kt   = out_keep + N_PTS;
    float* out_loss = out_kt + N_PTS;

    char* ws = (char*)d_ws;
    unsigned int* bmask   = (unsigned int*)(ws + 64);          // 128 KB -> 131136
    float*        thres   = (float*)(ws + 131136);             // 4 B

    k_gemm   <<<N_PTS / 64, 256, 0, stream>>>(fea, Wup, Wcls, out_pred, out_fea, bmask);
    k_selscat<<<1 + M_TGT / 1024, 1024, 0, stream>>>(out_pred, tcoords, bmask, thres);
    k_final  <<<N_PTS / 64, 256, 0, stream>>>(coords, bmask, thres,
                                              out_pred, out_fea, out_keep, out_kt, out_loss);
}